// Round 13
// baseline (3192.557 us; speedup 1.0000x reference)
//
#include <hip/hip_runtime.h>
#include <math.h>

#define BD 16384            // B*D
#define TT 512
#define KDIM 1024
#define NDIM 1024
#define GEMM_M 8192
#define PANEL_Q 320         // OpenBLAS SGEMM_DEFAULT_Q (SKYLAKEX/COOPERLAKE AVX512 path)
#define LOGE2F 0.69314718246459960938f
#define NGEMM 256           // gemm-role blocks
#define NTILE 6144          // 128 m-slabs x 16 n-tiles x 3 matrices
#define AGT __HIP_MEMORY_SCOPE_AGENT

// ===========================================================================
// Scan transcendentals: ROCm native f32 libm — FROZEN (r7-r12 passed).
// Compound arithmetic uses __fadd_rn/__fmul_rn/__fsub_rn to forbid FMA
// contraction. All value-producing formulas bit-identical to r12.
// ===========================================================================
__device__ __forceinline__ float np_expf(float x)   { return expf(x); }
__device__ __forceinline__ float np_logf(float x)   { return logf(x); }
__device__ __forceinline__ float np_log1pf(float x) { return log1pf(x); }

__device__ __forceinline__ float np_softplus(float v) {
    const float e  = np_expf(-fabsf(v));
    const float l1 = np_log1pf(e);
    const float r  = __fadd_rn(fmaxf(v, 0.0f), l1);
    return (v == 0.0f) ? LOGE2F : r;      // npy_logaddexpf x==y special case
}

__device__ __forceinline__ void np_sla(float la, float sa, float lb, float sb,
                                       float& lo, float& so) {
    bool az = la <= -39.0f;                  // LOG_ZERO + 1
    bool bz = lb <= -39.0f;
    float mx = fmaxf(la, lb);
    float mn = fminf(la, lb);
    float diff = __fsub_rn(mn, mx);
    bool amax = la >= lb;
    float smax = amax ? sa : sb;
    float smin = amax ? sb : sa;
    bool same = __fmul_rn(smax, smin) > 0.0f;
    float ed = np_expf(diff);
    float ls  = __fadd_rn(mx, np_log1pf(ed));
    float lop = __fadd_rn(mx, np_log1pf(-fminf(ed, 0.9999f)));
    float l = same ? ls : lop;
    float s = smax;
    l = az ? lb : l;  s = az ? sb : s;
    bool bo = bz && !az;
    l = bo ? la : l;  s = bo ? sa : s;
    lo = l; so = s;
}

__device__ __forceinline__ float ld_agent(const float* p) {
    return __hip_atomic_load(p, __ATOMIC_RELAXED, AGT);
}
__device__ __forceinline__ void st_agent(float* p, float v) {
    __hip_atomic_store(p, v, __ATOMIC_RELAXED, AGT);
}

// ===========================================================================
// FUSED persistent kernel: 512 blocks x 256 threads, all co-resident
// (2 blocks/CU: 28KB LDS, VGPR<=256 via launch_bounds(256,2)).
//   blocks [0,256):  GEMM role — 24 tiles each, slab-major order; per-element
//       arithmetic FROZEN (single-acc FMA chain, k ascending, Q=320 panels,
//       left-assoc fold, bias separate add). Outputs stored agent-scope;
//       done[slab] incremented with RELEASE after __syncthreads drain.
//   blocks [256,512): scan role — r12 3-wave structure (producer/consumer/
//       writer + 1 idle wave); producer spin-waits done[g+2]==48 (ACQUIRE),
//       loads via agent-scope atomic loads (bypass stale per-XCD L2).
// Scan arithmetic bit-identical to r12.
// ===========================================================================
__global__ __launch_bounds__(256, 2) void fused(
    const float* __restrict__ x,
    const float* __restrict__ Wa, const float* __restrict__ Wx, const float* __restrict__ Wd,
    const float* __restrict__ ba, const float* __restrict__ bx, const float* __restrict__ bd,
    const float* __restrict__ log_r_h, const float* __restrict__ sign_r_h,
    float* __restrict__ log_h, float* __restrict__ sign_h, float* __restrict__ h_lin,
    int* __restrict__ done)
{
    union SMem {
        struct { float As[16][68]; float Bs[16][68]; } g;     // 8.7 KB
        struct { float Xr[4][5][4][64]; float Or[4][2][4][64]; } s; // 28 KB
    };
    __shared__ SMem sm;

    if (blockIdx.x < NGEMM) {
        // ================= GEMM role =================
        const int tid = threadIdx.x;
        const int lr = tid >> 2;       // 0..63 staging row
        const int lc = tid & 3;        // float4 column
        const int ty = tid >> 4;       // 0..15 -> m = ty*4 + i
        const int tx = tid & 15;       // 0..15 -> n = tx*4 + j

        for (int T = blockIdx.x; T < NTILE; T += NGEMM) {
            const int m0i = T / 48;
            const int rem = T % 48;
            const int z   = rem >> 4;
            const int n0  = (rem & 15) * 64;
            const int m0  = m0i * 64;
            const float* W    = (z == 0) ? Wa : (z == 1) ? Wx : Wd;
            const float* bias = (z == 0) ? ba : (z == 1) ? bx : bd;
            // alpha_raw -> h_lin rows; lin -> log_h rows 1..; delta -> sign_h rows 1..
            float* out = (z == 0) ? h_lin : (z == 1) ? (log_h + BD) : (sign_h + BD);

            const float* Ap = x + (size_t)(m0 + lr) * KDIM + lc * 4;
            const float* Bp = W + (size_t)(n0 + lr) * KDIM + lc * 4;

            float4 fa = *(const float4*)Ap;
            float4 fb = *(const float4*)Bp;

            float tot[4][4], acc[4][4];
            #pragma unroll
            for (int i = 0; i < 4; ++i)
                #pragma unroll
                for (int j = 0; j < 4; ++j) { tot[i][j] = 0.0f; acc[i][j] = 0.0f; }

            for (int kt = 0; kt < KDIM; kt += 16) {
                if (kt == PANEL_Q || kt == 2 * PANEL_Q || kt == 3 * PANEL_Q) {
                    #pragma unroll
                    for (int i = 0; i < 4; ++i)
                        #pragma unroll
                        for (int j = 0; j < 4; ++j) {
                            tot[i][j] = __fadd_rn(tot[i][j], acc[i][j]);
                            acc[i][j] = 0.0f;
                        }
                }
                __syncthreads();
                {
                    const float* pa = (const float*)&fa;
                    const float* pb = (const float*)&fb;
                    #pragma unroll
                    for (int c = 0; c < 4; ++c) {
                        sm.g.As[lc * 4 + c][lr] = pa[c];
                        sm.g.Bs[lc * 4 + c][lr] = pb[c];
                    }
                }
                __syncthreads();
                if (kt + 16 < KDIM) {
                    fa = *(const float4*)(Ap + kt + 16);
                    fb = *(const float4*)(Bp + kt + 16);
                }
                #pragma unroll
                for (int kk = 0; kk < 16; ++kk) {          // k strictly ascending
                    const float4 a = *(const float4*)&sm.g.As[kk][ty * 4];
                    const float4 b = *(const float4*)&sm.g.Bs[kk][tx * 4];
                    const float av[4] = {a.x, a.y, a.z, a.w};
                    const float bv[4] = {b.x, b.y, b.z, b.w};
                    #pragma unroll
                    for (int i = 0; i < 4; ++i)
                        #pragma unroll
                        for (int j = 0; j < 4; ++j)
                            acc[i][j] = __fmaf_rn(av[i], bv[j], acc[i][j]);
                }
            }
            #pragma unroll
            for (int i = 0; i < 4; ++i)
                #pragma unroll
                for (int j = 0; j < 4; ++j)
                    tot[i][j] = __fadd_rn(tot[i][j], acc[i][j]);

            float bj[4];
            #pragma unroll
            for (int j = 0; j < 4; ++j) bj[j] = bias[n0 + tx * 4 + j];

            #pragma unroll
            for (int i = 0; i < 4; ++i) {
                float* op = out + (size_t)(m0 + ty * 4 + i) * NDIM + n0 + tx * 4;
                #pragma unroll
                for (int j = 0; j < 4; ++j)
                    st_agent(op + j, __fadd_rn(tot[i][j], bj[j]));
            }
            __syncthreads();   // drains all waves' stores (vmcnt0 before barrier)
            if (tid == 0)
                __hip_atomic_fetch_add(&done[m0i], 1, __ATOMIC_RELEASE, AGT);
        }
    } else {
        // ================= scan role =================
        const int sb = blockIdx.x - NGEMM;
        const int wv = threadIdx.x >> 6;   // 0..3 (wave 3 idles at barriers)
        const int ln = threadIdx.x & 63;
        const int idx = sb * 64 + ln;

#define WAIT_SLAB(S) do {                                                \
    int _guard = 0;                                                      \
    while (__hip_atomic_load(&done[S], __ATOMIC_ACQUIRE, AGT) < 48) {    \
        __builtin_amdgcn_s_sleep(2);                                     \
        if (++_guard > (1 << 27)) break;   /* safety valve: fail, not hang */ \
    } } while (0)

// Producer: agent-scope loads of group GG raws, xform -> Xr[GG&3].
// Formulas bit-identical to r8-r12 (passed).
#define LOAD_XFORM(GG) do {                                              \
    const int _s = (GG) & 3;                                             \
    const int _b = (GG) * 4;                                             \
    float ra[4], rl[4], rd[4];                                           \
    _Pragma("unroll")                                                    \
    for (int u = 0; u < 4; ++u) {                                        \
        ra[u] = ld_agent(h_lin  + (size_t)(_b + u) * BD + idx);          \
        rl[u] = ld_agent(log_h  + (size_t)(_b + u + 1) * BD + idx);      \
        rd[u] = ld_agent(sign_h + (size_t)(_b + u + 1) * BD + idx);      \
    }                                                                    \
    _Pragma("unroll")                                                    \
    for (int u = 0; u < 4; ++u) {                                        \
        sm.s.Xr[_s][0][u][ln] = __fadd_rn(1.0f, np_softplus(ra[u]));     \
        const float ax = fabsf(rl[u]);                                   \
        sm.s.Xr[_s][1][u][ln] = (ax > 1e-10f) ? np_logf(fmaxf(ax, 1e-10f)) \
                                              : -40.0f;                  \
        sm.s.Xr[_s][2][u][ln] = (rl[u] < 0.0f) ? -1.0f : 1.0f;           \
        const float dr = rd[u];                                          \
        const float e  = np_expf(-fabsf(dr));                            \
        const float l1 = np_log1pf(e);                                   \
        const float big = -__fadd_rn(fabsf(dr), l1);                     \
        const float sml = -l1;                                           \
        const float ld0 = (dr > 0.0f) ? sml : big;                       \
        const float lm0 = (dr > 0.0f) ? big : sml;                       \
        sm.s.Xr[_s][3][u][ln] = (dr == 0.0f) ? -LOGE2F : ld0;            \
        sm.s.Xr[_s][4][u][ln] = (dr == 0.0f) ? -LOGE2F : lm0;            \
    } } while (0)

#define WRITE_GROUP(GG) do {                                             \
    const int _s = (GG) & 3;                                             \
    _Pragma("unroll")                                                    \
    for (int u = 0; u < 4; ++u) {                                        \
        const int t = (GG) * 4 + u;                                      \
        const float lhn = sm.s.Or[_s][0][u][ln];                         \
        const float shn = sm.s.Or[_s][1][u][ln];                         \
        const float res = __fmul_rn(shn, np_expf(fminf(lhn, 20.0f)));    \
        const float h = (lhn > -39.0f) ? res : 0.0f;                     \
        log_h[(size_t)(t + 1) * BD + idx] = lhn;                         \
        sign_h[(size_t)(t + 1) * BD + idx] = shn;                        \
        h_lin[(size_t)t * BD + idx] = h;                                 \
    } } while (0)

        // ---- prologue ----
        float lrh = 0.0f, srh = 0.0f;
        if (wv == 0) {
            WAIT_SLAB(0);
            LOAD_XFORM(0);
            WAIT_SLAB(1);
            LOAD_XFORM(1);
        } else if (wv == 1) {
            const int d = idx & 1023;
            lrh = log_r_h[d];
            srh = sign_r_h[d];
        } else if (wv == 2) {
            log_h[idx] = -40.0f;        // row 0
            sign_h[idx] = 1.0f;
        }
        __syncthreads();

        float lhp = -40.0f, shp = 1.0f;

        for (int g = 0; g < 128; ++g) {
            if (wv == 0) {
                if (g + 2 < 128) {
                    WAIT_SLAB(g + 2);
                    LOAD_XFORM(g + 2);
                }
            } else if (wv == 1) {
                const int s = g & 3;
                float xa[4], xli[4], xsi[4], xld[4], xlm[4];
                #pragma unroll
                for (int u = 0; u < 4; ++u) {
                    xa[u]  = sm.s.Xr[s][0][u][ln];
                    xli[u] = sm.s.Xr[s][1][u][ln];
                    xsi[u] = sm.s.Xr[s][2][u][ln];
                    xld[u] = sm.s.Xr[s][3][u][ln];
                    xlm[u] = sm.s.Xr[s][4][u][ln];
                }
                #pragma unroll
                for (int u = 0; u < 4; ++u) {   // serial chain (bit-frozen)
                    const float log_rh  = __fadd_rn(lrh, lhp);
                    const float sign_rh = __fmul_rn(srh, shp);
                    float lv, sv;
                    np_sla(log_rh, sign_rh, xli[u], xsi[u], lv, sv);
                    const float tt = __fmul_rn(xa[u], lv);
                    const float log_cand = -np_softplus(-tt);
                    float lhn, shn;
                    np_sla(__fadd_rn(xlm[u], lhp), shp,
                           __fadd_rn(xld[u], log_cand), sv, lhn, shn);
                    sm.s.Or[s][0][u][ln] = lhn;
                    sm.s.Or[s][1][u][ln] = shn;
                    lhp = lhn; shp = shn;
                }
            } else if (wv == 2) {
                if (g > 0) WRITE_GROUP(g - 1);
            }
            __syncthreads();
        }
        if (wv == 2) WRITE_GROUP(127);

#undef WAIT_SLAB
#undef LOAD_XFORM
#undef WRITE_GROUP
    }
}

// ===========================================================================
extern "C" void kernel_launch(void* const* d_in, const int* in_sizes, int n_in,
                              void* d_out, int out_size, void* d_ws, size_t ws_size,
                              hipStream_t stream) {
    const float* x        = (const float*)d_in[0];
    const float* W_x      = (const float*)d_in[1];
    const float* W_alpha  = (const float*)d_in[2];
    const float* W_delta  = (const float*)d_in[3];
    const float* b        = (const float*)d_in[4];
    const float* b_alpha  = (const float*)d_in[5];
    const float* b_delta  = (const float*)d_in[6];
    const float* log_r_h  = (const float*)d_in[7];
    const float* sign_r_h = (const float*)d_in[8];

    float* out    = (float*)d_out;
    float* log_h  = out;                            // [513, BD]
    float* sign_h = out + (size_t)513 * BD;         // [513, BD]
    float* h_lin  = out + (size_t)2 * 513 * BD;     // [512, BD]

    int* done = (int*)d_ws;                          // 128 slab counters
    hipMemsetAsync(done, 0, 128 * sizeof(int), stream);

    fused<<<dim3(NGEMM + 256), dim3(256), 0, stream>>>(
        x, W_alpha, W_x, W_delta, b_alpha, b, b_delta,
        log_r_h, sign_r_h, log_h, sign_h, h_lin, done);
}

// Round 14
// 1335.226 us; speedup vs baseline: 2.3910x; 2.3910x over previous
//
#include <hip/hip_runtime.h>
#include <math.h>

#define BD 16384            // B*D
#define TT 512
#define KDIM 1024
#define NDIM 1024
#define GEMM_M 8192
#define PANEL_Q 320         // OpenBLAS SGEMM_DEFAULT_Q (SKYLAKEX/COOPERLAKE AVX512 path)
#define LOGE2F 0.69314718246459960938f

// ===========================================================================
// Scan transcendentals: ROCm native f32 libm — FROZEN (r7-r12 passed).
// Compound arithmetic uses __fadd_rn/__fmul_rn/__fsub_rn to forbid FMA
// contraction. All value-producing formulas bit-identical to r12.
// ===========================================================================
__device__ __forceinline__ float np_expf(float x)   { return expf(x); }
__device__ __forceinline__ float np_logf(float x)   { return logf(x); }
__device__ __forceinline__ float np_log1pf(float x) { return log1pf(x); }

__device__ __forceinline__ float np_softplus(float v) {
    const float e  = np_expf(-fabsf(v));
    const float l1 = np_log1pf(e);
    const float r  = __fadd_rn(fmaxf(v, 0.0f), l1);
    return (v == 0.0f) ? LOGE2F : r;      // npy_logaddexpf x==y special case
}

__device__ __forceinline__ void np_sla(float la, float sa, float lb, float sb,
                                       float& lo, float& so) {
    bool az = la <= -39.0f;                  // LOG_ZERO + 1
    bool bz = lb <= -39.0f;
    float mx = fmaxf(la, lb);
    float mn = fminf(la, lb);
    float diff = __fsub_rn(mn, mx);
    bool amax = la >= lb;
    float smax = amax ? sa : sb;
    float smin = amax ? sb : sa;
    bool same = __fmul_rn(smax, smin) > 0.0f;
    float ed = np_expf(diff);
    float ls  = __fadd_rn(mx, np_log1pf(ed));
    float lop = __fadd_rn(mx, np_log1pf(-fminf(ed, 0.9999f)));
    float l = same ? ls : lop;
    float s = smax;
    l = az ? lb : l;  s = az ? sb : s;
    bool bo = bz && !az;
    l = bo ? la : l;  s = bo ? sa : s;
    lo = l; so = s;
}

// ===========================================================================
// OpenBLAS-sgemm-exact NT-GEMM. Per-element arithmetic FROZEN (r7-r12):
// single-accumulator FMA chain, k strictly ascending, split at Q=320 panel
// boundaries {320,320,320,64}, partials folded left-assoc, bias as one
// separate f32 add. NEW memory schedule only: 128x128 block tile, 8x8 per
// thread (256 threads) — 4x less non-FMA VALU glue per FMA than r12's 64x64.
// ===========================================================================
__global__ __launch_bounds__(256) void gemm_blas(
    const float* __restrict__ x,
    const float* __restrict__ Wa, const float* __restrict__ Wx, const float* __restrict__ Wd,
    const float* __restrict__ ba, const float* __restrict__ bx, const float* __restrict__ bd,
    float* __restrict__ out_a, float* __restrict__ out_x, float* __restrict__ out_d)
{
    const int z = blockIdx.z;
    const float* W    = (z == 0) ? Wa : (z == 1) ? Wx : Wd;
    const float* bias = (z == 0) ? ba : (z == 1) ? bx : bd;
    float* out        = (z == 0) ? out_a : (z == 1) ? out_x : out_d;

    const int m0 = blockIdx.x * 128;
    const int n0 = blockIdx.y * 128;

    __shared__ float As[16][132];  // [k in tile][m]
    __shared__ float Bs[16][132];  // [k in tile][n]

    const int tid = threadIdx.x;
    const int lr = tid >> 2;       // 0..63 staging row
    const int lc = tid & 3;        // float4 column within BK=16
    const int ty = tid >> 4;       // 0..15 -> m = ty*8 + i
    const int tx = tid & 15;       // 0..15 -> n = tx*8 + j

    const float* Ap = x + (size_t)(m0 + lr) * KDIM + lc * 4;
    const float* Bp = W + (size_t)(n0 + lr) * KDIM + lc * 4;

    float4 aR0 = *(const float4*)(Ap);
    float4 aR1 = *(const float4*)(Ap + (size_t)64 * KDIM);
    float4 bR0 = *(const float4*)(Bp);
    float4 bR1 = *(const float4*)(Bp + (size_t)64 * KDIM);

    float tot[8][8];               // folded finished panels
    float acc[8][8];               // current panel FMA chain
    #pragma unroll
    for (int i = 0; i < 8; ++i)
        #pragma unroll
        for (int j = 0; j < 8; ++j) { tot[i][j] = 0.0f; acc[i][j] = 0.0f; }

    for (int kt = 0; kt < KDIM; kt += 16) {
        if (kt == PANEL_Q || kt == 2 * PANEL_Q || kt == 3 * PANEL_Q) {
            #pragma unroll
            for (int i = 0; i < 8; ++i)
                #pragma unroll
                for (int j = 0; j < 8; ++j) {
                    tot[i][j] = __fadd_rn(tot[i][j], acc[i][j]);  // C += panel
                    acc[i][j] = 0.0f;
                }
        }
        __syncthreads();
        {
            const float* a0 = (const float*)&aR0;
            const float* a1 = (const float*)&aR1;
            const float* b0 = (const float*)&bR0;
            const float* b1 = (const float*)&bR1;
            #pragma unroll
            for (int c = 0; c < 4; ++c) {
                As[lc * 4 + c][lr]      = a0[c];
                As[lc * 4 + c][lr + 64] = a1[c];
                Bs[lc * 4 + c][lr]      = b0[c];
                Bs[lc * 4 + c][lr + 64] = b1[c];
            }
        }
        __syncthreads();
        if (kt + 16 < KDIM) {      // prefetch next K-slab under compute
            aR0 = *(const float4*)(Ap + kt + 16);
            aR1 = *(const float4*)(Ap + (size_t)64 * KDIM + kt + 16);
            bR0 = *(const float4*)(Bp + kt + 16);
            bR1 = *(const float4*)(Bp + (size_t)64 * KDIM + kt + 16);
        }
        #pragma unroll
        for (int kk = 0; kk < 16; ++kk) {          // k strictly ascending
            const float4 a0 = *(const float4*)&As[kk][ty * 8];
            const float4 a1 = *(const float4*)&As[kk][ty * 8 + 4];
            const float4 b0 = *(const float4*)&Bs[kk][tx * 8];
            const float4 b1 = *(const float4*)&Bs[kk][tx * 8 + 4];
            const float av[8] = {a0.x, a0.y, a0.z, a0.w, a1.x, a1.y, a1.z, a1.w};
            const float bv[8] = {b0.x, b0.y, b0.z, b0.w, b1.x, b1.y, b1.z, b1.w};
            #pragma unroll
            for (int i = 0; i < 8; ++i)
                #pragma unroll
                for (int j = 0; j < 8; ++j)
                    acc[i][j] = __fmaf_rn(av[i], bv[j], acc[i][j]);
        }
    }
    #pragma unroll
    for (int i = 0; i < 8; ++i)                    // fold last (64-wide) panel
        #pragma unroll
        for (int j = 0; j < 8; ++j)
            tot[i][j] = __fadd_rn(tot[i][j], acc[i][j]);

    float bj[8];
    #pragma unroll
    for (int j = 0; j < 8; ++j) bj[j] = bias[n0 + tx * 8 + j];

    #pragma unroll
    for (int i = 0; i < 8; ++i) {
        float* op = out + (size_t)(m0 + ty * 8 + i) * NDIM + n0 + tx * 8;
        float4 v0, v1;
        v0.x = __fadd_rn(tot[i][0], bj[0]); v0.y = __fadd_rn(tot[i][1], bj[1]);
        v0.z = __fadd_rn(tot[i][2], bj[2]); v0.w = __fadd_rn(tot[i][3], bj[3]);
        v1.x = __fadd_rn(tot[i][4], bj[4]); v1.y = __fadd_rn(tot[i][5], bj[5]);
        v1.z = __fadd_rn(tot[i][6], bj[6]); v1.w = __fadd_rn(tot[i][7], bj[7]);
        *(float4*)(op)     = v0;
        *(float4*)(op + 4) = v1;
    }
}

// ===========================================================================
// f32 scan — byte-for-byte the r12 kernel (745 µs, passed). 3 waves/block:
// producer (gl_lds ring + counted vmcnt + xform, 2 groups ahead), consumer
// (serial recurrence, LDS-only), writer (epilogue + global stores, 1 behind).
// ===========================================================================
__device__ __forceinline__ void gl_lds(const float* g, float* l) {
    __builtin_amdgcn_global_load_lds(
        (const __attribute__((address_space(1))) void*)g,
        (__attribute__((address_space(3))) void*)l, 4, 0, 0);
}

#define WAITVM(N) do {                                                   \
    asm volatile("s_waitcnt vmcnt(" #N ")" ::: "memory");                \
    __builtin_amdgcn_sched_barrier(0); } while (0)

__global__ __launch_bounds__(192, 1) void scan_kernel(
    float* __restrict__ log_h, float* __restrict__ sign_h, float* __restrict__ h_lin,
    const float* __restrict__ log_r_h, const float* __restrict__ sign_r_h)
{
    __shared__ float Xr[4][5][4][64];   // [slot][a,li,si,ld,lm][u][lane]  20 KB
    __shared__ float Or[4][2][4][64];   // [slot][lhn,shn][u][lane]         8 KB
    __shared__ float Rr[4][12][64];     // raw ring (producer only)        12 KB

    const int wv = threadIdx.x >> 6;
    const int ln = threadIdx.x & 63;
    const int idx = blockIdx.x * 64 + ln;

#define ISSUE_LOADS(GG, SL) do {                                         \
    const int _b = (GG) * 4;                                             \
    _Pragma("unroll")                                                    \
    for (int u = 0; u < 4; ++u) {                                        \
        gl_lds(h_lin  + (size_t)(_b + u) * BD + idx,     &Rr[SL][u * 3 + 0][0]); \
        gl_lds(log_h  + (size_t)(_b + u + 1) * BD + idx, &Rr[SL][u * 3 + 1][0]); \
        gl_lds(sign_h + (size_t)(_b + u + 1) * BD + idx, &Rr[SL][u * 3 + 2][0]); \
    } } while (0)

#define XFORM_TO(GG) do {                                                \
    const int _s = (GG) & 3;                                             \
    _Pragma("unroll")                                                    \
    for (int u = 0; u < 4; ++u) {                                        \
        const float araw = Rr[_s][u * 3 + 0][ln];                        \
        const float lin  = Rr[_s][u * 3 + 1][ln];                        \
        const float dr   = Rr[_s][u * 3 + 2][ln];                        \
        Xr[_s][0][u][ln] = __fadd_rn(1.0f, np_softplus(araw));           \
        const float ax = fabsf(lin);                                     \
        Xr[_s][1][u][ln] = (ax > 1e-10f) ? np_logf(fmaxf(ax, 1e-10f))    \
                                         : -40.0f;                       \
        Xr[_s][2][u][ln] = (lin < 0.0f) ? -1.0f : 1.0f;                  \
        const float e  = np_expf(-fabsf(dr));                            \
        const float l1 = np_log1pf(e);                                   \
        const float big = -__fadd_rn(fabsf(dr), l1);                     \
        const float sml = -l1;                                           \
        const float ld0 = (dr > 0.0f) ? sml : big;                       \
        const float lm0 = (dr > 0.0f) ? big : sml;                       \
        Xr[_s][3][u][ln] = (dr == 0.0f) ? -LOGE2F : ld0;                 \
        Xr[_s][4][u][ln] = (dr == 0.0f) ? -LOGE2F : lm0;                 \
    } } while (0)

#define WRITE_GROUP(GG) do {                                             \
    const int _s = (GG) & 3;                                             \
    _Pragma("unroll")                                                    \
    for (int u = 0; u < 4; ++u) {                                        \
        const int t = (GG) * 4 + u;                                      \
        const float lhn = Or[_s][0][u][ln];                              \
        const float shn = Or[_s][1][u][ln];                              \
        const float res = __fmul_rn(shn, np_expf(fminf(lhn, 20.0f)));    \
        const float h = (lhn > -39.0f) ? res : 0.0f;                     \
        log_h[(size_t)(t + 1) * BD + idx] = lhn;                         \
        sign_h[(size_t)(t + 1) * BD + idx] = shn;                        \
        h_lin[(size_t)t * BD + idx] = h;                                 \
    } } while (0)

    // ---- prologue ----
    float lrh = 0.0f, srh = 0.0f;
    if (wv == 1) {
        const int d = idx & 1023;
        lrh = log_r_h[d];
        srh = sign_r_h[d];
    } else if (wv == 0) {
        ISSUE_LOADS(0, 0);
        ISSUE_LOADS(1, 1);
        WAITVM(0);
        XFORM_TO(0);
        XFORM_TO(1);
        ISSUE_LOADS(2, 2);          // in flight across the barrier
    } else {
        log_h[idx] = -40.0f;        // row 0
        sign_h[idx] = 1.0f;
    }
    __syncthreads();

    float lhp = -40.0f, shp = 1.0f;

    for (int g = 0; g < 128; ++g) {
        if (wv == 0) {
            // FIFO before wait: loads(g+2)[12 old] | loads(g+3)[12 new]
            const int gl = (g + 3 < 128) ? g + 3 : 127;   // dead-slot clamp
            ISSUE_LOADS(gl, (g + 3) & 3);
            WAITVM(12);                                    // loads(g+2) done
            if (g + 2 < 128) XFORM_TO(g + 2);
        } else if (wv == 1) {
            const int s = g & 3;
            float xa[4], xli[4], xsi[4], xld[4], xlm[4];
            #pragma unroll
            for (int u = 0; u < 4; ++u) {
                xa[u]  = Xr[s][0][u][ln];
                xli[u] = Xr[s][1][u][ln];
                xsi[u] = Xr[s][2][u][ln];
                xld[u] = Xr[s][3][u][ln];
                xlm[u] = Xr[s][4][u][ln];
            }
            #pragma unroll
            for (int u = 0; u < 4; ++u) {       // serial chain (bit-frozen)
                const float log_rh  = __fadd_rn(lrh, lhp);
                const float sign_rh = __fmul_rn(srh, shp);
                float lv, sv;
                np_sla(log_rh, sign_rh, xli[u], xsi[u], lv, sv);
                const float tt = __fmul_rn(xa[u], lv);
                const float log_cand = -np_softplus(-tt);
                float lhn, shn;
                np_sla(__fadd_rn(xlm[u], lhp), shp,
                       __fadd_rn(xld[u], log_cand), sv, lhn, shn);
                Or[s][0][u][ln] = lhn;
                Or[s][1][u][ln] = shn;
                lhp = lhn; shp = shn;
            }
        } else {
            if (g > 0) WRITE_GROUP(g - 1);
        }
        __syncthreads();
    }
    if (wv == 2) WRITE_GROUP(127);   // last loop barrier orders Or[3]

#undef ISSUE_LOADS
#undef XFORM_TO
#undef WRITE_GROUP
}

// ===========================================================================
extern "C" void kernel_launch(void* const* d_in, const int* in_sizes, int n_in,
                              void* d_out, int out_size, void* d_ws, size_t ws_size,
                              hipStream_t stream) {
    const float* x        = (const float*)d_in[0];
    const float* W_x      = (const float*)d_in[1];
    const float* W_alpha  = (const float*)d_in[2];
    const float* W_delta  = (const float*)d_in[3];
    const float* b        = (const float*)d_in[4];
    const float* b_alpha  = (const float*)d_in[5];
    const float* b_delta  = (const float*)d_in[6];
    const float* log_r_h  = (const float*)d_in[7];
    const float* sign_r_h = (const float*)d_in[8];

    float* out    = (float*)d_out;
    float* log_h  = out;                            // [513, BD]
    float* sign_h = out + (size_t)513 * BD;         // [513, BD]
    float* h_lin  = out + (size_t)2 * 513 * BD;     // [512, BD]

    dim3 ggrid(GEMM_M / 128, NDIM / 128, 3);
    gemm_blas<<<ggrid, dim3(256), 0, stream>>>(
        x, W_alpha, W_x, W_delta, b_alpha, b, b_delta,
        h_lin, log_h + BD, sign_h + BD);

    scan_kernel<<<dim3(BD / 64), dim3(192), 0, stream>>>(
        log_h, sign_h, h_lin, log_r_h, sign_r_h);
}

// Round 15
// 1161.404 us; speedup vs baseline: 2.7489x; 1.1497x over previous
//
#include <hip/hip_runtime.h>
#include <math.h>

#define BD 16384            // B*D
#define TT 512
#define KDIM 1024
#define NDIM 1024
#define GEMM_M 8192
#define PANEL_Q 320         // OpenBLAS SGEMM_DEFAULT_Q (SKYLAKEX/COOPERLAKE AVX512 path)
#define LOGE2F 0.69314718246459960938f

// ===========================================================================
// Scan transcendentals: ROCm native f32 libm — FROZEN (r7-r14 passed).
// Compound arithmetic uses __fadd_rn/__fmul_rn/__fsub_rn to forbid FMA
// contraction.
// ===========================================================================
__device__ __forceinline__ float np_expf(float x)   { return expf(x); }
__device__ __forceinline__ float np_logf(float x)   { return logf(x); }
__device__ __forceinline__ float np_log1pf(float x) { return log1pf(x); }

__device__ __forceinline__ float np_softplus(float v) {
    const float e  = np_expf(-fabsf(v));
    const float l1 = np_log1pf(e);
    const float r  = __fadd_rn(fmaxf(v, 0.0f), l1);
    return (v == 0.0f) ? LOGE2F : r;      // npy_logaddexpf x==y special case
}

// signed_log_add. BIT-IDENTICAL to r12 but with select-before-log1p: the
// reference computes log1p(ed) and log1p(-min(ed,0.9999)) then selects; we
// select the ARGUMENT then call log1p once — the selected result is the
// same f32 value bit-for-bit, one fewer transcendental body on the chain.
__device__ __forceinline__ void np_sla(float la, float sa, float lb, float sb,
                                       float& lo, float& so) {
    bool az = la <= -39.0f;                  // LOG_ZERO + 1
    bool bz = lb <= -39.0f;
    float mx = fmaxf(la, lb);
    float mn = fminf(la, lb);
    float diff = __fsub_rn(mn, mx);
    bool amax = la >= lb;
    float smax = amax ? sa : sb;
    float smin = amax ? sb : sa;
    bool same = __fmul_rn(smax, smin) > 0.0f;
    float ed = np_expf(diff);
    float arg = same ? ed : -fminf(ed, 0.9999f);
    float l = __fadd_rn(mx, np_log1pf(arg));
    float s = smax;
    l = az ? lb : l;  s = az ? sb : s;
    bool bo = bz && !az;
    l = bo ? la : l;  s = bo ? sa : s;
    lo = l; so = s;
}

// ===========================================================================
// OpenBLAS-sgemm-exact NT-GEMM. Per-element arithmetic FROZEN (r7-r14):
// single-accumulator FMA chain, k strictly ascending, Q=320 panel folds
// {320,320,320,64} left-assoc, bias as one separate f32 add.
// Memory schedule: 128x128 block tile, 8x8 per thread via SPLIT mapping
// (rows ty*4+{0..3} U 64+ty*4+{0..3}; cols likewise) — all ds_read_b128 at
// stride 4 floats => 2-way bank aliasing (free), vs r14's 4-way at stride 8.
// ===========================================================================
__global__ __launch_bounds__(256) void gemm_blas(
    const float* __restrict__ x,
    const float* __restrict__ Wa, const float* __restrict__ Wx, const float* __restrict__ Wd,
    const float* __restrict__ ba, const float* __restrict__ bx, const float* __restrict__ bd,
    float* __restrict__ out_a, float* __restrict__ out_x, float* __restrict__ out_d)
{
    const int z = blockIdx.z;
    const float* W    = (z == 0) ? Wa : (z == 1) ? Wx : Wd;
    const float* bias = (z == 0) ? ba : (z == 1) ? bx : bd;
    float* out        = (z == 0) ? out_a : (z == 1) ? out_x : out_d;

    const int m0 = blockIdx.x * 128;
    const int n0 = blockIdx.y * 128;

    __shared__ float As[16][132];  // [k in tile][m]
    __shared__ float Bs[16][132];  // [k in tile][n]

    const int tid = threadIdx.x;
    const int lr = tid >> 2;       // 0..63 staging row
    const int lc = tid & 3;        // float4 column within BK=16
    const int ty = tid >> 4;       // 0..15
    const int tx = tid & 15;       // 0..15

    const float* Ap = x + (size_t)(m0 + lr) * KDIM + lc * 4;
    const float* Bp = W + (size_t)(n0 + lr) * KDIM + lc * 4;

    float4 aR0 = *(const float4*)(Ap);
    float4 aR1 = *(const float4*)(Ap + (size_t)64 * KDIM);
    float4 bR0 = *(const float4*)(Bp);
    float4 bR1 = *(const float4*)(Bp + (size_t)64 * KDIM);

    float tot[8][8];               // folded finished panels
    float acc[8][8];               // current panel FMA chain
    #pragma unroll
    for (int i = 0; i < 8; ++i)
        #pragma unroll
        for (int j = 0; j < 8; ++j) { tot[i][j] = 0.0f; acc[i][j] = 0.0f; }

    for (int kt = 0; kt < KDIM; kt += 16) {
        if (kt == PANEL_Q || kt == 2 * PANEL_Q || kt == 3 * PANEL_Q) {
            #pragma unroll
            for (int i = 0; i < 8; ++i)
                #pragma unroll
                for (int j = 0; j < 8; ++j) {
                    tot[i][j] = __fadd_rn(tot[i][j], acc[i][j]);  // C += panel
                    acc[i][j] = 0.0f;
                }
        }
        __syncthreads();
        {
            const float* a0 = (const float*)&aR0;
            const float* a1 = (const float*)&aR1;
            const float* b0 = (const float*)&bR0;
            const float* b1 = (const float*)&bR1;
            #pragma unroll
            for (int c = 0; c < 4; ++c) {
                As[lc * 4 + c][lr]      = a0[c];
                As[lc * 4 + c][lr + 64] = a1[c];
                Bs[lc * 4 + c][lr]      = b0[c];
                Bs[lc * 4 + c][lr + 64] = b1[c];
            }
        }
        __syncthreads();
        if (kt + 16 < KDIM) {      // prefetch next K-slab under compute
            aR0 = *(const float4*)(Ap + kt + 16);
            aR1 = *(const float4*)(Ap + (size_t)64 * KDIM + kt + 16);
            bR0 = *(const float4*)(Bp + kt + 16);
            bR1 = *(const float4*)(Bp + (size_t)64 * KDIM + kt + 16);
        }
        #pragma unroll
        for (int kk = 0; kk < 16; ++kk) {          // k strictly ascending
            const float4 a0 = *(const float4*)&As[kk][ty * 4];        // rows ty*4+i
            const float4 a1 = *(const float4*)&As[kk][64 + ty * 4];   // rows 64+ty*4+i
            const float4 b0 = *(const float4*)&Bs[kk][tx * 4];        // cols tx*4+j
            const float4 b1 = *(const float4*)&Bs[kk][64 + tx * 4];   // cols 64+tx*4+j
            const float av[8] = {a0.x, a0.y, a0.z, a0.w, a1.x, a1.y, a1.z, a1.w};
            const float bv[8] = {b0.x, b0.y, b0.z, b0.w, b1.x, b1.y, b1.z, b1.w};
            #pragma unroll
            for (int i = 0; i < 8; ++i)
                #pragma unroll
                for (int j = 0; j < 8; ++j)
                    acc[i][j] = __fmaf_rn(av[i], bv[j], acc[i][j]);
        }
    }
    #pragma unroll
    for (int i = 0; i < 8; ++i)                    // fold last (64-wide) panel
        #pragma unroll
        for (int j = 0; j < 8; ++j)
            tot[i][j] = __fadd_rn(tot[i][j], acc[i][j]);

    float bj[8];
    #pragma unroll
    for (int j = 0; j < 4; ++j) {
        bj[j]     = bias[n0 + tx * 4 + j];
        bj[4 + j] = bias[n0 + 64 + tx * 4 + j];
    }

    #pragma unroll
    for (int h = 0; h < 2; ++h) {                  // row halves: ty*4 / 64+ty*4
        #pragma unroll
        for (int i = 0; i < 4; ++i) {
            const int mi = h * 4 + i;
            float* op = out + (size_t)(m0 + h * 64 + ty * 4 + i) * NDIM + n0;
            float4 v0, v1;
            v0.x = __fadd_rn(tot[mi][0], bj[0]); v0.y = __fadd_rn(tot[mi][1], bj[1]);
            v0.z = __fadd_rn(tot[mi][2], bj[2]); v0.w = __fadd_rn(tot[mi][3], bj[3]);
            v1.x = __fadd_rn(tot[mi][4], bj[4]); v1.y = __fadd_rn(tot[mi][5], bj[5]);
            v1.z = __fadd_rn(tot[mi][6], bj[6]); v1.w = __fadd_rn(tot[mi][7], bj[7]);
            *(float4*)(op + tx * 4)      = v0;
            *(float4*)(op + 64 + tx * 4) = v1;
        }
    }
}

// ===========================================================================
// f32 scan — r12 3-wave structure (producer / consumer / writer), consumer
// now 6 libm bodies/step via select-before-log1p np_sla (bit-identical).
// ===========================================================================
__device__ __forceinline__ void gl_lds(const float* g, float* l) {
    __builtin_amdgcn_global_load_lds(
        (const __attribute__((address_space(1))) void*)g,
        (__attribute__((address_space(3))) void*)l, 4, 0, 0);
}

#define WAITVM(N) do {                                                   \
    asm volatile("s_waitcnt vmcnt(" #N ")" ::: "memory");                \
    __builtin_amdgcn_sched_barrier(0); } while (0)

__global__ __launch_bounds__(192, 1) void scan_kernel(
    float* __restrict__ log_h, float* __restrict__ sign_h, float* __restrict__ h_lin,
    const float* __restrict__ log_r_h, const float* __restrict__ sign_r_h)
{
    __shared__ float Xr[4][5][4][64];   // [slot][a,li,si,ld,lm][u][lane]  20 KB
    __shared__ float Or[4][2][4][64];   // [slot][lhn,shn][u][lane]         8 KB
    __shared__ float Rr[4][12][64];     // raw ring (producer only)        12 KB

    const int wv = threadIdx.x >> 6;
    const int ln = threadIdx.x & 63;
    const int idx = blockIdx.x * 64 + ln;

#define ISSUE_LOADS(GG, SL) do {                                         \
    const int _b = (GG) * 4;                                             \
    _Pragma("unroll")                                                    \
    for (int u = 0; u < 4; ++u) {                                        \
        gl_lds(h_lin  + (size_t)(_b + u) * BD + idx,     &Rr[SL][u * 3 + 0][0]); \
        gl_lds(log_h  + (size_t)(_b + u + 1) * BD + idx, &Rr[SL][u * 3 + 1][0]); \
        gl_lds(sign_h + (size_t)(_b + u + 1) * BD + idx, &Rr[SL][u * 3 + 2][0]); \
    } } while (0)

#define XFORM_TO(GG) do {                                                \
    const int _s = (GG) & 3;                                             \
    _Pragma("unroll")                                                    \
    for (int u = 0; u < 4; ++u) {                                        \
        const float araw = Rr[_s][u * 3 + 0][ln];                        \
        const float lin  = Rr[_s][u * 3 + 1][ln];                        \
        const float dr   = Rr[_s][u * 3 + 2][ln];                        \
        Xr[_s][0][u][ln] = __fadd_rn(1.0f, np_softplus(araw));           \
        const float ax = fabsf(lin);                                     \
        Xr[_s][1][u][ln] = (ax > 1e-10f) ? np_logf(fmaxf(ax, 1e-10f))    \
                                         : -40.0f;                       \
        Xr[_s][2][u][ln] = (lin < 0.0f) ? -1.0f : 1.0f;                  \
        const float e  = np_expf(-fabsf(dr));                            \
        const float l1 = np_log1pf(e);                                   \
        const float big = -__fadd_rn(fabsf(dr), l1);                     \
        const float sml = -l1;                                           \
        const float ld0 = (dr > 0.0f) ? sml : big;                       \
        const float lm0 = (dr > 0.0f) ? big : sml;                       \
        Xr[_s][3][u][ln] = (dr == 0.0f) ? -LOGE2F : ld0;                 \
        Xr[_s][4][u][ln] = (dr == 0.0f) ? -LOGE2F : lm0;                 \
    } } while (0)

#define WRITE_GROUP(GG) do {                                             \
    const int _s = (GG) & 3;                                             \
    _Pragma("unroll")                                                    \
    for (int u = 0; u < 4; ++u) {                                        \
        const int t = (GG) * 4 + u;                                      \
        const float lhn = Or[_s][0][u][ln];                              \
        const float shn = Or[_s][1][u][ln];                              \
        const float res = __fmul_rn(shn, np_expf(fminf(lhn, 20.0f)));    \
        const float h = (lhn > -39.0f) ? res : 0.0f;                     \
        log_h[(size_t)(t + 1) * BD + idx] = lhn;                         \
        sign_h[(size_t)(t + 1) * BD + idx] = shn;                        \
        h_lin[(size_t)t * BD + idx] = h;                                 \
    } } while (0)

    // ---- prologue ----
    float lrh = 0.0f, srh = 0.0f;
    if (wv == 1) {
        const int d = idx & 1023;
        lrh = log_r_h[d];
        srh = sign_r_h[d];
    } else if (wv == 0) {
        ISSUE_LOADS(0, 0);
        ISSUE_LOADS(1, 1);
        WAITVM(0);
        XFORM_TO(0);
        XFORM_TO(1);
        ISSUE_LOADS(2, 2);          // in flight across the barrier
    } else {
        log_h[idx] = -40.0f;        // row 0
        sign_h[idx] = 1.0f;
    }
    __syncthreads();

    float lhp = -40.0f, shp = 1.0f;

    for (int g = 0; g < 128; ++g) {
        if (wv == 0) {
            // FIFO before wait: loads(g+2)[12 old] | loads(g+3)[12 new]
            const int gl = (g + 3 < 128) ? g + 3 : 127;   // dead-slot clamp
            ISSUE_LOADS(gl, (g + 3) & 3);
            WAITVM(12);                                    // loads(g+2) done
            if (g + 2 < 128) XFORM_TO(g + 2);
        } else if (wv == 1) {
            const int s = g & 3;
            float xa[4], xli[4], xsi[4], xld[4], xlm[4];
            #pragma unroll
            for (int u = 0; u < 4; ++u) {
                xa[u]  = Xr[s][0][u][ln];
                xli[u] = Xr[s][1][u][ln];
                xsi[u] = Xr[s][2][u][ln];
                xld[u] = Xr[s][3][u][ln];
                xlm[u] = Xr[s][4][u][ln];
            }
            #pragma unroll
            for (int u = 0; u < 4; ++u) {       // serial chain (bit-frozen)
                const float log_rh  = __fadd_rn(lrh, lhp);
                const float sign_rh = __fmul_rn(srh, shp);
                float lv, sv;
                np_sla(log_rh, sign_rh, xli[u], xsi[u], lv, sv);
                const float tt = __fmul_rn(xa[u], lv);
                const float log_cand = -np_softplus(-tt);
                float lhn, shn;
                np_sla(__fadd_rn(xlm[u], lhp), shp,
                       __fadd_rn(xld[u], log_cand), sv, lhn, shn);
                Or[s][0][u][ln] = lhn;
                Or[s][1][u][ln] = shn;
                lhp = lhn; shp = shn;
            }
        } else {
            if (g > 0) WRITE_GROUP(g - 1);
        }
        __syncthreads();
    }
    if (wv == 2) WRITE_GROUP(127);   // last loop barrier orders Or[3]

#undef ISSUE_LOADS
#undef XFORM_TO
#undef WRITE_GROUP
}

// ===========================================================================
extern "C" void kernel_launch(void* const* d_in, const int* in_sizes, int n_in,
                              void* d_out, int out_size, void* d_ws, size_t ws_size,
                              hipStream_t stream) {
    const float* x        = (const float*)d_in[0];
    const float* W_x      = (const float*)d_in[1];
    const float* W_alpha  = (const float*)d_in[2];
    const float* W_delta  = (const float*)d_in[3];
    const float* b        = (const float*)d_in[4];
    const float* b_alpha  = (const float*)d_in[5];
    const float* b_delta  = (const float*)d_in[6];
    const float* log_r_h  = (const float*)d_in[7];
    const float* sign_r_h = (const float*)d_in[8];

    float* out    = (float*)d_out;
    float* log_h  = out;                            // [513, BD]
    float* sign_h = out + (size_t)513 * BD;         // [513, BD]
    float* h_lin  = out + (size_t)2 * 513 * BD;     // [512, BD]

    dim3 ggrid(GEMM_M / 128, NDIM / 128, 3);
    gemm_blas<<<ggrid, dim3(256), 0, stream>>>(
        x, W_alpha, W_x, W_delta, b_alpha, b, b_delta,
        h_lin, log_h + BD, sign_h + BD);

    scan_kernel<<<dim3(BD / 64), dim3(192), 0, stream>>>(
        log_h, sign_h, h_lin, log_r_h, sign_r_h);
}

// Round 16
// 1124.789 us; speedup vs baseline: 2.8384x; 1.0326x over previous
//
#include <hip/hip_runtime.h>
#include <math.h>

#define BD 16384            // B*D
#define TT 512
#define KDIM 1024
#define NDIM 1024
#define GEMM_M 8192
#define PANEL_Q 320         // OpenBLAS SGEMM_DEFAULT_Q (SKYLAKEX/COOPERLAKE AVX512 path)
#define LOGE2F 0.69314718246459960938f

// ===========================================================================
// Scan transcendentals: ROCm native f32 libm — FROZEN (r7-r15 passed).
// Compound arithmetic uses __fadd_rn/__fmul_rn/__fsub_rn to forbid FMA
// contraction.
// ===========================================================================
__device__ __forceinline__ float np_expf(float x)   { return expf(x); }
__device__ __forceinline__ float np_logf(float x)   { return logf(x); }
__device__ __forceinline__ float np_log1pf(float x) { return log1pf(x); }

__device__ __forceinline__ float np_softplus(float v) {
    const float e  = np_expf(-fabsf(v));
    const float l1 = np_log1pf(e);
    const float r  = __fadd_rn(fmaxf(v, 0.0f), l1);
    return (v == 0.0f) ? LOGE2F : r;      // npy_logaddexpf x==y special case
}

// signed_log_add with select-before-log1p (bit-identical to the reference's
// compute-both-then-select; r15 passed with this).
__device__ __forceinline__ void np_sla(float la, float sa, float lb, float sb,
                                       float& lo, float& so) {
    bool az = la <= -39.0f;                  // LOG_ZERO + 1
    bool bz = lb <= -39.0f;
    float mx = fmaxf(la, lb);
    float mn = fminf(la, lb);
    float diff = __fsub_rn(mn, mx);
    bool amax = la >= lb;
    float smax = amax ? sa : sb;
    float smin = amax ? sb : sa;
    bool same = __fmul_rn(smax, smin) > 0.0f;
    float ed = np_expf(diff);
    float arg = same ? ed : -fminf(ed, 0.9999f);
    float l = __fadd_rn(mx, np_log1pf(arg));
    float s = smax;
    l = az ? lb : l;  s = az ? sb : s;
    bool bo = bz && !az;
    l = bo ? la : l;  s = bo ? sa : s;
    lo = l; so = s;
}

// ===========================================================================
// OpenBLAS-sgemm-exact NT-GEMM. Per-element arithmetic FROZEN (r7-r15):
// single-accumulator FMA chain, k strictly ascending, Q=320 panel folds
// {320,320,320,64} left-assoc, bias as one separate f32 add.
// Memory schedule: 128x64 block tile, 8x4 per thread (split row mapping:
// rows ty*4+{0..3} U 64+ty*4+{0..3}; cols tx*4+{0..3}) — 32 FMA per 3
// ds_read_b128, all stride-4 (2-way aliasing, free). Accumulator state is
// 64 VGPR; __launch_bounds__(256,4) caps allocation at 128 VGPR so 4 waves
// per SIMD co-reside and hide LDS/barrier latency (r15 had 1).
// ===========================================================================
__global__ __launch_bounds__(256, 4) void gemm_blas(
    const float* __restrict__ x,
    const float* __restrict__ Wa, const float* __restrict__ Wx, const float* __restrict__ Wd,
    const float* __restrict__ ba, const float* __restrict__ bx, const float* __restrict__ bd,
    float* __restrict__ out_a, float* __restrict__ out_x, float* __restrict__ out_d)
{
    const int z = blockIdx.z;
    const float* W    = (z == 0) ? Wa : (z == 1) ? Wx : Wd;
    const float* bias = (z == 0) ? ba : (z == 1) ? bx : bd;
    float* out        = (z == 0) ? out_a : (z == 1) ? out_x : out_d;

    const int m0 = blockIdx.x * 128;
    const int n0 = blockIdx.y * 64;

    __shared__ float As[16][132];  // [k in tile][m]  (128 rows + pad)
    __shared__ float Bs[16][68];   // [k in tile][n]  (64 cols + pad)

    const int tid = threadIdx.x;
    const int lr = tid >> 2;       // 0..63 staging row
    const int lc = tid & 3;        // float4 column within BK=16
    const int ty = tid >> 4;       // 0..15 -> rows ty*4+i, 64+ty*4+i
    const int tx = tid & 15;       // 0..15 -> cols tx*4+j

    const float* Ap = x + (size_t)(m0 + lr) * KDIM + lc * 4;
    const float* Bp = W + (size_t)(n0 + lr) * KDIM + lc * 4;

    float4 aR0 = *(const float4*)(Ap);
    float4 aR1 = *(const float4*)(Ap + (size_t)64 * KDIM);
    float4 bR0 = *(const float4*)(Bp);

    float tot[8][4];               // folded finished panels
    float acc[8][4];               // current panel FMA chain
    #pragma unroll
    for (int i = 0; i < 8; ++i)
        #pragma unroll
        for (int j = 0; j < 4; ++j) { tot[i][j] = 0.0f; acc[i][j] = 0.0f; }

    for (int kt = 0; kt < KDIM; kt += 16) {
        if (kt == PANEL_Q || kt == 2 * PANEL_Q || kt == 3 * PANEL_Q) {
            #pragma unroll
            for (int i = 0; i < 8; ++i)
                #pragma unroll
                for (int j = 0; j < 4; ++j) {
                    tot[i][j] = __fadd_rn(tot[i][j], acc[i][j]);  // C += panel
                    acc[i][j] = 0.0f;
                }
        }
        __syncthreads();
        {
            const float* a0 = (const float*)&aR0;
            const float* a1 = (const float*)&aR1;
            const float* b0 = (const float*)&bR0;
            #pragma unroll
            for (int c = 0; c < 4; ++c) {
                As[lc * 4 + c][lr]      = a0[c];
                As[lc * 4 + c][lr + 64] = a1[c];
                Bs[lc * 4 + c][lr]      = b0[c];
            }
        }
        __syncthreads();
        if (kt + 16 < KDIM) {      // prefetch next K-slab under compute
            aR0 = *(const float4*)(Ap + kt + 16);
            aR1 = *(const float4*)(Ap + (size_t)64 * KDIM + kt + 16);
            bR0 = *(const float4*)(Bp + kt + 16);
        }
        #pragma unroll
        for (int kk = 0; kk < 16; ++kk) {          // k strictly ascending
            const float4 a0 = *(const float4*)&As[kk][ty * 4];        // rows ty*4+i
            const float4 a1 = *(const float4*)&As[kk][64 + ty * 4];   // rows 64+ty*4+i
            const float4 b0 = *(const float4*)&Bs[kk][tx * 4];        // cols tx*4+j
            const float av[8] = {a0.x, a0.y, a0.z, a0.w, a1.x, a1.y, a1.z, a1.w};
            const float bv[4] = {b0.x, b0.y, b0.z, b0.w};
            #pragma unroll
            for (int i = 0; i < 8; ++i)
                #pragma unroll
                for (int j = 0; j < 4; ++j)
                    acc[i][j] = __fmaf_rn(av[i], bv[j], acc[i][j]);
        }
    }
    #pragma unroll
    for (int i = 0; i < 8; ++i)                    // fold last (64-wide) panel
        #pragma unroll
        for (int j = 0; j < 4; ++j)
            tot[i][j] = __fadd_rn(tot[i][j], acc[i][j]);

    float bj[4];
    #pragma unroll
    for (int j = 0; j < 4; ++j) bj[j] = bias[n0 + tx * 4 + j];

    #pragma unroll
    for (int h = 0; h < 2; ++h) {                  // row halves: ty*4 / 64+ty*4
        #pragma unroll
        for (int i = 0; i < 4; ++i) {
            const int mi = h * 4 + i;
            float* op = out + (size_t)(m0 + h * 64 + ty * 4 + i) * NDIM + n0 + tx * 4;
            float4 v;
            v.x = __fadd_rn(tot[mi][0], bj[0]);
            v.y = __fadd_rn(tot[mi][1], bj[1]);
            v.z = __fadd_rn(tot[mi][2], bj[2]);
            v.w = __fadd_rn(tot[mi][3], bj[3]);
            *(float4*)op = v;
        }
    }
}

// ===========================================================================
// f32 scan — byte-for-byte r15 (passed): 3-wave structure (producer /
// consumer / writer), consumer 6 libm bodies/step via select-before-log1p.
// ===========================================================================
__device__ __forceinline__ void gl_lds(const float* g, float* l) {
    __builtin_amdgcn_global_load_lds(
        (const __attribute__((address_space(1))) void*)g,
        (__attribute__((address_space(3))) void*)l, 4, 0, 0);
}

#define WAITVM(N) do {                                                   \
    asm volatile("s_waitcnt vmcnt(" #N ")" ::: "memory");                \
    __builtin_amdgcn_sched_barrier(0); } while (0)

__global__ __launch_bounds__(192, 1) void scan_kernel(
    float* __restrict__ log_h, float* __restrict__ sign_h, float* __restrict__ h_lin,
    const float* __restrict__ log_r_h, const float* __restrict__ sign_r_h)
{
    __shared__ float Xr[4][5][4][64];   // [slot][a,li,si,ld,lm][u][lane]  20 KB
    __shared__ float Or[4][2][4][64];   // [slot][lhn,shn][u][lane]         8 KB
    __shared__ float Rr[4][12][64];     // raw ring (producer only)        12 KB

    const int wv = threadIdx.x >> 6;
    const int ln = threadIdx.x & 63;
    const int idx = blockIdx.x * 64 + ln;

#define ISSUE_LOADS(GG, SL) do {                                         \
    const int _b = (GG) * 4;                                             \
    _Pragma("unroll")                                                    \
    for (int u = 0; u < 4; ++u) {                                        \
        gl_lds(h_lin  + (size_t)(_b + u) * BD + idx,     &Rr[SL][u * 3 + 0][0]); \
        gl_lds(log_h  + (size_t)(_b + u + 1) * BD + idx, &Rr[SL][u * 3 + 1][0]); \
        gl_lds(sign_h + (size_t)(_b + u + 1) * BD + idx, &Rr[SL][u * 3 + 2][0]); \
    } } while (0)

#define XFORM_TO(GG) do {                                                \
    const int _s = (GG) & 3;                                             \
    _Pragma("unroll")                                                    \
    for (int u = 0; u < 4; ++u) {                                        \
        const float araw = Rr[_s][u * 3 + 0][ln];                        \
        const float lin  = Rr[_s][u * 3 + 1][ln];                        \
        const float dr   = Rr[_s][u * 3 + 2][ln];                        \
        Xr[_s][0][u][ln] = __fadd_rn(1.0f, np_softplus(araw));           \
        const float ax = fabsf(lin);                                     \
        Xr[_s][1][u][ln] = (ax > 1e-10f) ? np_logf(fmaxf(ax, 1e-10f))    \
                                         : -40.0f;                       \
        Xr[_s][2][u][ln] = (lin < 0.0f) ? -1.0f : 1.0f;                  \
        const float e  = np_expf(-fabsf(dr));                            \
        const float l1 = np_log1pf(e);                                   \
        const float big = -__fadd_rn(fabsf(dr), l1);                     \
        const float sml = -l1;                                           \
        const float ld0 = (dr > 0.0f) ? sml : big;                       \
        const float lm0 = (dr > 0.0f) ? big : sml;                       \
        Xr[_s][3][u][ln] = (dr == 0.0f) ? -LOGE2F : ld0;                 \
        Xr[_s][4][u][ln] = (dr == 0.0f) ? -LOGE2F : lm0;                 \
    } } while (0)

#define WRITE_GROUP(GG) do {                                             \
    const int _s = (GG) & 3;                                             \
    _Pragma("unroll")                                                    \
    for (int u = 0; u < 4; ++u) {                                        \
        const int t = (GG) * 4 + u;                                      \
        const float lhn = Or[_s][0][u][ln];                              \
        const float shn = Or[_s][1][u][ln];                              \
        const float res = __fmul_rn(shn, np_expf(fminf(lhn, 20.0f)));    \
        const float h = (lhn > -39.0f) ? res : 0.0f;                     \
        log_h[(size_t)(t + 1) * BD + idx] = lhn;                         \
        sign_h[(size_t)(t + 1) * BD + idx] = shn;                        \
        h_lin[(size_t)t * BD + idx] = h;                                 \
    } } while (0)

    // ---- prologue ----
    float lrh = 0.0f, srh = 0.0f;
    if (wv == 1) {
        const int d = idx & 1023;
        lrh = log_r_h[d];
        srh = sign_r_h[d];
    } else if (wv == 0) {
        ISSUE_LOADS(0, 0);
        ISSUE_LOADS(1, 1);
        WAITVM(0);
        XFORM_TO(0);
        XFORM_TO(1);
        ISSUE_LOADS(2, 2);          // in flight across the barrier
    } else {
        log_h[idx] = -40.0f;        // row 0
        sign_h[idx] = 1.0f;
    }
    __syncthreads();

    float lhp = -40.0f, shp = 1.0f;

    for (int g = 0; g < 128; ++g) {
        if (wv == 0) {
            // FIFO before wait: loads(g+2)[12 old] | loads(g+3)[12 new]
            const int gl = (g + 3 < 128) ? g + 3 : 127;   // dead-slot clamp
            ISSUE_LOADS(gl, (g + 3) & 3);
            WAITVM(12);                                    // loads(g+2) done
            if (g + 2 < 128) XFORM_TO(g + 2);
        } else if (wv == 1) {
            const int s = g & 3;
            float xa[4], xli[4], xsi[4], xld[4], xlm[4];
            #pragma unroll
            for (int u = 0; u < 4; ++u) {
                xa[u]  = Xr[s][0][u][ln];
                xli[u] = Xr[s][1][u][ln];
                xsi[u] = Xr[s][2][u][ln];
                xld[u] = Xr[s][3][u][ln];
                xlm[u] = Xr[s][4][u][ln];
            }
            #pragma unroll
            for (int u = 0; u < 4; ++u) {       // serial chain (bit-frozen)
                const float log_rh  = __fadd_rn(lrh, lhp);
                const float sign_rh = __fmul_rn(srh, shp);
                float lv, sv;
                np_sla(log_rh, sign_rh, xli[u], xsi[u], lv, sv);
                const float tt = __fmul_rn(xa[u], lv);
                const float log_cand = -np_softplus(-tt);
                float lhn, shn;
                np_sla(__fadd_rn(xlm[u], lhp), shp,
                       __fadd_rn(xld[u], log_cand), sv, lhn, shn);
                Or[s][0][u][ln] = lhn;
                Or[s][1][u][ln] = shn;
                lhp = lhn; shp = shn;
            }
        } else {
            if (g > 0) WRITE_GROUP(g - 1);
        }
        __syncthreads();
    }
    if (wv == 2) WRITE_GROUP(127);   // last loop barrier orders Or[3]

#undef ISSUE_LOADS
#undef XFORM_TO
#undef WRITE_GROUP
}

// ===========================================================================
extern "C" void kernel_launch(void* const* d_in, const int* in_sizes, int n_in,
                              void* d_out, int out_size, void* d_ws, size_t ws_size,
                              hipStream_t stream) {
    const float* x        = (const float*)d_in[0];
    const float* W_x      = (const float*)d_in[1];
    const float* W_alpha  = (const float*)d_in[2];
    const float* W_delta  = (const float*)d_in[3];
    const float* b        = (const float*)d_in[4];
    const float* b_alpha  = (const float*)d_in[5];
    const float* b_delta  = (const float*)d_in[6];
    const float* log_r_h  = (const float*)d_in[7];
    const float* sign_r_h = (const float*)d_in[8];

    float* out    = (float*)d_out;
    float* log_h  = out;                            // [513, BD]
    float* sign_h = out + (size_t)513 * BD;         // [513, BD]
    float* h_lin  = out + (size_t)2 * 513 * BD;     // [512, BD]

    dim3 ggrid(GEMM_M / 128, NDIM / 64, 3);
    gemm_blas<<<ggrid, dim3(256), 0, stream>>>(
        x, W_alpha, W_x, W_delta, b_alpha, b, b_delta,
        h_lin, log_h + BD, sign_h + BD);

    scan_kernel<<<dim3(BD / 64), dim3(192), 0, stream>>>(
        log_h, sign_h, h_lin, log_r_h, sign_r_h);
}